// Round 11
// baseline (908.442 us; speedup 1.0000x reference)
//
#include <hip/hip_runtime.h>

// CRF Viterbi decode: B=256, T=512, K=256, out (B, 514) as int32 tags.
//
// Session-pinned facts (gfx950):
//  - Unified RF: 128 regs/thread at 4 waves/EU, split arch-VGPR/AGPR.
//  - VOP3 (v_add_f32/v_max3_f32) CAN read AGPR srcs free; VOP3P
//    (v_pk_add_f32) CANNOT (r9 assembler reject).
//  - asm "v" constraints on AGPR-allocated values => copy storms (r7/r8/r10).
//  - Compiler never fuses fmaxf pairs into v_max3, never emits pk_add.
//  - r5 (pure-C scalar) == scalar issue roofline: 128 compute insts/step.
//
// fwd: one block/batch, 16 waves. Wave w=(g,p): g=w>>1 owns i-rows
// [32g,32g+32), p=w&1 owns j-half; lane owns cols {j0,j0+1}, j0=128p+2*lane.
// Payload: 32 v2f over i from transT, PINNED TO ARCH VGPRS via "+v" no-op
// asm => v_pk_add_f32 legal, max3 copy-free. Inner: 16 x {2 uniform b64
// state reads, 2 pk_add, 2 tied max3} = 64 VALU/thread/step (1 per update).
// ONE raw s_barrier per step, lgkmcnt(0)-only (vmcnt never drained in-loop).
// part[] double-buffered => race-free single-barrier scheme (r8-validated).
// bwd: separate kernel (fusion cost +70us, r10), exact f32 equality scan.
// ws: states[B*T*K] f32 (128 MiB) + transT[K*K] f32 (256 KiB).

#define TK 256
#define TT 512

typedef float v2f __attribute__((ext_vector_type(2)));

__device__ __forceinline__ void max3acc(float& acc, float a, float b) {
  asm("v_max3_f32 %0, %0, %1, %2" : "+v"(acc) : "v"(a), "v"(b));
}

__device__ __forceinline__ v2f pk_add(v2f a, v2f b) {
  v2f d;
  asm("v_pk_add_f32 %0, %1, %2" : "=v"(d) : "v"(a), "v"(b));
  return d;
}

__global__ void transpose_kernel(const float* __restrict__ trans,
                                 float* __restrict__ transT) {
  int j = blockIdx.x;
  int i = threadIdx.x;
  transT[(size_t)j * TK + i] = trans[(size_t)i * TK + j];
}

__global__ __launch_bounds__(1024)
__attribute__((amdgpu_waves_per_eu(4, 4)))
void crf_fwd(const float* __restrict__ em,
             const float* __restrict__ transT,
             const int* __restrict__ mask,
             float* __restrict__ states) {
  const int b = blockIdx.x;
  const int tid = threadIdx.x;
  const int lane = tid & 63;
  const int w = tid >> 6;    // wave 0..15
  const int g = w >> 1;      // i-rows [32g, 32g+32)
  const int p = w & 1;       // j-half
  const int j0 = 128 * p + 2 * lane;  // compute-phase cols {j0, j0+1}

  __shared__ __align__(16) float st_w[16][32];        // wave-private state
  __shared__ float part[2][8][2][2][64];              // dbuf partials, 16 KiB
  __shared__ int mk[TT];

  // payload: TA_n = {tr[32g+2n][j0], tr[32g+2n+1][j0]}, TB_n same for j0+1
  const float* ta = transT + (size_t)j0 * TK + 32 * g;
  const float* tbq = ta + TK;
#define K16(X) X(0) X(1) X(2) X(3) X(4) X(5) X(6) X(7) \
               X(8) X(9) X(10) X(11) X(12) X(13) X(14) X(15)
#define TRD(n) \
  v2f TA##n = *reinterpret_cast<const v2f*>(ta + 2 * (n)); \
  v2f TB##n = *reinterpret_cast<const v2f*>(tbq + 2 * (n)); \
  asm("" : "+v"(TA##n)); \
  asm("" : "+v"(TB##n));
  K16(TRD)
#undef TRD

  if (tid < TT) mk[tid] = mask[(size_t)b * TT + tid];

  const size_t base = (size_t)b * TT * TK;
  // fold-phase constants (lanes<32 handle j = 32g + lane)
  const int pj = g >> 2;
  const int sel = lane & 1;
  const int col = 16 * (g & 3) + (lane >> 1);

  float ns = 0.f, e1 = 0.f, e2 = 0.f;
  if (lane < 32) {
    ns = em[base + 32 * g + lane];           // state0 = emissions[:,0,:]
    st_w[w][lane] = ns;
    if (p == 0) states[base + 32 * g + lane] = ns;
    e1 = em[base + TK + 32 * g + lane];      // em row 1
    e2 = em[base + 2 * TK + 32 * g + lane];  // em row 2
  }
  __syncthreads();  // mk + st_w init visible (full drain OK once)

  const float* emp = em + base + 3 * TK + 32 * g + lane;  // row t+2 at t=1
  float* stg = states + base + TK + 32 * g + lane;        // row t (p==0)
  const float* sw = st_w[w];

  for (int t = 1; t < TT; ++t) {
    // ---- compute: 16 x {2 b64 uniform reads, 2 pk_add, 2 max3} ----
    float ax, ay;
    {
      const v2f SP = *reinterpret_cast<const v2f*>(sw);
      const v2f cA = pk_add(TA0, SP);
      const v2f cB = pk_add(TB0, SP);
      ax = fmaxf(cA.x, cA.y);
      ay = fmaxf(cB.x, cB.y);
    }
#define ROWK(n)                                                    \
    if ((n) > 0) {                                                 \
      const v2f SP = *reinterpret_cast<const v2f*>(sw + 2 * (n));  \
      const v2f cA = pk_add(TA##n, SP);                            \
      const v2f cB = pk_add(TB##n, SP);                            \
      max3acc(ax, cA.x, cA.y);                                     \
      max3acc(ay, cB.x, cB.y);                                     \
    }
    K16(ROWK)
#undef ROWK
#undef K16

    // two b32 part writes, banks = lane%32, 2-way (free)
    float* pw = &part[t & 1][g][p][0][lane];
    pw[0] = ax;
    pw[64] = ay;

    // ---- single barrier: LDS-only wait, vmcnt stays in flight ----
    asm volatile("s_waitcnt lgkmcnt(0)" ::: "memory");
    __builtin_amdgcn_s_barrier();

    // ---- fold phase (lanes<32): j = 32g+lane ----
    if (lane < 32) {
      const float* pf = &part[t & 1][0][pj][sel][col];
      const float f0 = pf[0];
      const float f1 = pf[256];
      const float f2 = pf[512];
      const float f3 = pf[768];
      const float f4 = pf[1024];
      const float f5 = pf[1280];
      const float f6 = pf[1536];
      const float f7 = pf[1792];
      float f = fmaxf(f0, f1);
      max3acc(f, f2, f3);
      max3acc(f, f4, f5);
      max3acc(f, f6, f7);
      ns = (mk[t] > 0) ? (f + e1) : ns;
      st_w[w][lane] = ns;
      if (p == 0) *stg = ns;
      stg += TK;
      e1 = e2;
      if (t + 2 < TT) e2 = *emp;
      emp += TK;
    }
  }
}

__device__ __forceinline__ float wave_max(float m) {
#pragma unroll
  for (int d = 1; d < 64; d <<= 1) m = fmaxf(m, __shfl_xor(m, d, 64));
  return m;
}

// First index i (lane-major: i = 4*lane + k) whose value equals m.
__device__ __forceinline__ int first_eq_idx(float s0, float s1, float s2,
                                            float s3, float m) {
  unsigned long long b0 = __ballot(s0 == m);
  unsigned long long b1 = __ballot(s1 == m);
  unsigned long long b2 = __ballot(s2 == m);
  unsigned long long b3 = __ballot(s3 == m);
  int best = 0x7fffffff;
  if (b0) best = min(best, 4 * (__ffsll(b0) - 1) + 0);
  if (b1) best = min(best, 4 * (__ffsll(b1) - 1) + 1);
  if (b2) best = min(best, 4 * (__ffsll(b2) - 1) + 2);
  if (b3) best = min(best, 4 * (__ffsll(b3) - 1) + 3);
  return best;
}

// Backward: one wave per batch; 511 serial steps. Recomputes the forward
// argmax exactly (f32 add/max bit-exact; first-occurrence tie-break).
__global__ __launch_bounds__(64, 1) void crf_bwd(const float* __restrict__ states,
                                                 const float* __restrict__ transT,
                                                 const int* __restrict__ mask,
                                                 int* __restrict__ out,
                                                 int out_stride) {
  const int b = blockIdx.x;
  const int lane = threadIdx.x;

  __shared__ int mk[TT];
  for (int q = lane; q < TT; q += 64) mk[q] = mask[(size_t)b * TT + q];
  __syncthreads();

  const size_t sbase = (size_t)b * TT * TK;
  int* outp = out + (size_t)b * out_stride;

  // zero the pad region (harness poisons d_out once)
  for (int q = TT + lane; q < out_stride; q += 64) outp[q] = 0;

  const float* srow = states + sbase;
  float4 r = *reinterpret_cast<const float4*>(srow + (size_t)(TT - 1) * TK + 4 * lane);
  float lm = fmaxf(fmaxf(r.x, r.y), fmaxf(r.z, r.w));
  lm = wave_max(lm);
  int tag = first_eq_idx(r.x, r.y, r.z, r.w, lm);

  auto LOADROW = [&](int rr) -> float4 {
    return *reinterpret_cast<const float4*>(srow + (size_t)rr * TK + 4 * lane);
  };
  float4 p0 = LOADROW(TT - 2), p1 = LOADROW(TT - 3), p2 = LOADROW(TT - 4),
         p3 = LOADROW(TT - 5);

  auto STEP = [&](float4 pr, int t) {
    int mkt = mk[t];
    if (lane == 0) outp[t] = (mkt > 0) ? tag : 0;  // tags * mask
    const float4 tv =
        *reinterpret_cast<const float4*>(transT + (size_t)tag * TK + 4 * lane);
    float s0 = pr.x + tv.x;
    float s1 = pr.y + tv.y;
    float s2 = pr.z + tv.z;
    float s3 = pr.w + tv.w;
    float m = fmaxf(fmaxf(s0, s1), fmaxf(s2, s3));
    m = wave_max(m);
    int prev = first_eq_idx(s0, s1, s2, s3, m);
    tag = (mkt > 0) ? prev : tag;
  };

  int t = TT - 1;
  while (t >= 4) {
    STEP(p0, t);     if (t - 5 >= 0) p0 = LOADROW(t - 5);
    STEP(p1, t - 1); if (t - 6 >= 0) p1 = LOADROW(t - 6);
    STEP(p2, t - 2); if (t - 7 >= 0) p2 = LOADROW(t - 7);
    STEP(p3, t - 3); if (t - 8 >= 0) p3 = LOADROW(t - 8);
    t -= 4;
  }
  STEP(p0, 3);
  STEP(p1, 2);
  STEP(p2, 1);
  if (lane == 0) outp[0] = (mk[0] > 0) ? tag : 0;
}

extern "C" void kernel_launch(void* const* d_in, const int* in_sizes, int n_in,
                              void* d_out, int out_size, void* d_ws, size_t ws_size,
                              hipStream_t stream) {
  const float* em = (const float*)d_in[0];
  const float* trans = (const float*)d_in[1];
  const int* mask = (const int*)d_in[2];
  int* out = (int*)d_out;

  const int B = in_sizes[0] / (TT * TK);      // 256
  const int out_stride = out_size / B;        // 514

  float* states = (float*)d_ws;
  float* transT = states + (size_t)B * TT * TK;

  transpose_kernel<<<TK, TK, 0, stream>>>(trans, transT);
  crf_fwd<<<B, 1024, 0, stream>>>(em, transT, mask, states);
  crf_bwd<<<B, 64, 0, stream>>>(states, transT, mask, out, out_stride);
}